// Round 7
// baseline (243.797 us; speedup 1.0000x reference)
//
#include <hip/hip_runtime.h>
#include <math.h>

namespace {

constexpr int B_ = 8;
constexpr int C_ = 256;
constexpr int N_ = 4096;

constexpr int TM = 64;    // m-rows per attn block
constexpr int TN = 128;   // n-chunk per iteration
constexpr int NCH = N_ / TN;
constexpr int PSTRIDE = 136;  // ps row stride in bf16 (16B-aligned rows)
constexpr float LOG2E = 1.4426950408889634f;

typedef __attribute__((ext_vector_type(8))) short short8;    // 8 bf16
typedef __attribute__((ext_vector_type(16))) float float16;  // 16 fp32 acc

__device__ inline unsigned short f2bf(float f) {
  unsigned u = __float_as_uint(f);
  u += 0x7FFFu + ((u >> 16) & 1u);   // RNE
  return (unsigned short)(u >> 16);
}
__device__ inline float bf2f(unsigned short h) {
  return __uint_as_float(((unsigned)h) << 16);
}
// NOTE (R6 post-mortem): do NOT use inline-asm v_exp_f32 — the transcendental
// result-hazard slack is compiler-managed; asm hides it and corrupts results.
// exp2f at -O3 already lowers to a bare v_exp_f32 with correct scheduling.

// ---- prep: wv -> bf16 ; wqk A-matrix [wq*log2e hi(8); lo(8); wk hi(8); lo(8)] ----
__global__ __launch_bounds__(256) void prep_kernel(
    const float* __restrict__ wv, const float* __restrict__ wq,
    const float* __restrict__ wk,
    unsigned short* __restrict__ wv_bf, unsigned short* __restrict__ wqk_bf) {
  const int i = blockIdx.x * 256 + threadIdx.x;   // grid 256 -> 65536 threads
  wv_bf[i] = f2bf(wv[i]);
  if (i < 2048) {
    const int d = i >> 8, c = i & 255;
    const float qL = wq[i] * LOG2E;
    const unsigned short hq = f2bf(qL);
    wqk_bf[d * 256 + c]        = hq;
    wqk_bf[(d + 8) * 256 + c]  = f2bf(qL - bf2f(hq));
    const float kv = wk[i];
    const unsigned short hk = f2bf(kv);
    wqk_bf[(d + 16) * 256 + c] = hk;
    wqk_bf[(d + 24) * 256 + c] = f2bf(kv - bf2f(hk));
  }
}

// Build a bf16 B-fragment (8 consecutive k=c values at column n) from fp32 LDS.
__device__ inline short8 xfrag(const float* xs, int c0, int n) {
  short8 r;
  #pragma unroll
  for (int i = 0; i < 8; ++i) r[i] = (short)f2bf(xs[(c0 + i) * 32 + n]);
  return r;
}

// ---- fused projection, all-MFMA, async-staged ----
// Tile = [256 c][32 n] fp32 (32 KB LDS). Each global_load_lds covers 2 c-rows
// (per-lane global addresses; LDS dest = uniform base + lane*4). 1024 blocks,
// 4 blocks/CU -> load/compute phases of neighbors interleave.
__global__ __launch_bounds__(256, 4) void proj_kernel(
    const float* __restrict__ x,
    const float* __restrict__ bq, const float* __restrict__ bk,
    const unsigned short* __restrict__ wqk_bf,
    const unsigned short* __restrict__ wv_bf, const float* __restrict__ bv,
    unsigned short* __restrict__ q_t, unsigned short* __restrict__ k_th,
    unsigned short* __restrict__ k_tl, unsigned short* __restrict__ v)
{
  __shared__ float xs[256 * 32];   // [c][n] fp32, 32 KB

  const int b = blockIdx.y;
  const int n0 = blockIdx.x * 32;
  const int tid = threadIdx.x;
  const int w = tid >> 6, l = tid & 63;
  const int l31 = l & 31, lh = l >> 5;

  // async stage: wave w covers c rows [64w, 64w+64), 2 rows per instruction
  {
    const int c_off = l >> 5, nn = l & 31;
    const float* gp = x + ((size_t)b * C_ + w * 64 + c_off) * N_ + n0 + nn;
    const float* lp = xs + (w * 64) * 32;
    #pragma unroll
    for (int i = 0; i < 64; i += 2) {
      __builtin_amdgcn_global_load_lds(
          (const __attribute__((address_space(1))) void*)(gp + (size_t)i * N_),
          (__attribute__((address_space(3))) void*)(lp + i * 32), 4, 0, 0);
    }
  }
  __syncthreads();   // drains vmcnt before barrier

  // q/k MFMA: wave 0 only -> D[32 d-rows][32 n]
  if (w == 0) {
    float16 sacc;
    #pragma unroll
    for (int r = 0; r < 16; ++r) sacc[r] = 0.f;
    for (int ks = 0; ks < 16; ++ks) {
      const short8 a = *reinterpret_cast<const short8*>(
          wqk_bf + l31 * 256 + ks * 16 + lh * 8);
      const short8 bfg = xfrag(xs, ks * 16 + lh * 8, l31);
      sacc = __builtin_amdgcn_mfma_f32_32x32x16_bf16(a, bfg, sacc, 0, 0, 0);
    }
    // rows: d=q_hi, d+8=q_lo, d+16=k_hi, d+24=k_lo ; lane holds d = r+4*lh, r<4
    const size_t gn = (size_t)b * N_ + n0 + l31;
    #pragma unroll
    for (int r = 0; r < 4; ++r) {
      const int d = r + 4 * lh;
      const float qv = sacc[r] + sacc[r + 4] + bq[d] * LOG2E;
      const unsigned short hq = f2bf(qv);
      q_t[gn * 16 + d]     = hq;
      q_t[gn * 16 + 8 + d] = f2bf(qv - bf2f(hq));
      const float kv = sacc[r + 8] + sacc[r + 12] + bk[d];
      const unsigned short hk = f2bf(kv);
      k_th[gn * 8 + d] = hk;
      k_tl[gn * 8 + d] = f2bf(kv - bf2f(hk));
    }
  }

  // V: wave w -> c_out [64w, 64w+64) x n [0,32): 2 accs of 32x32
  float16 acc[2];
  #pragma unroll
  for (int mi = 0; mi < 2; ++mi)
    #pragma unroll
    for (int r = 0; r < 16; ++r) acc[mi][r] = 0.f;

  for (int ks = 0; ks < 16; ++ks) {
    short8 af[2];
    #pragma unroll
    for (int mi = 0; mi < 2; ++mi)
      af[mi] = *reinterpret_cast<const short8*>(
          wv_bf + (w * 64 + mi * 32 + l31) * C_ + ks * 16 + lh * 8);
    const short8 bfg = xfrag(xs, ks * 16 + lh * 8, l31);
    #pragma unroll
    for (int mi = 0; mi < 2; ++mi)
      acc[mi] = __builtin_amdgcn_mfma_f32_32x32x16_bf16(af[mi], bfg, acc[mi], 0, 0, 0);
  }

  #pragma unroll
  for (int mi = 0; mi < 2; ++mi)
    #pragma unroll
    for (int r = 0; r < 16; ++r) {
      const int c = w * 64 + mi * 32 + (r & 3) + 8 * (r >> 2) + 4 * lh;
      v[((size_t)b * C_ + c) * N_ + n0 + l31] = f2bf(acc[mi][r] + bv[c]);
    }
}

// ---- fused attention, barrier-pipelined ----
// Epoch nc between barriers: PV(chunk nc) from ps[buf]  +  QK/exp(chunk nc+1)
// into ps[buf^1]. exp VALU overlaps PV MFMA (separate pipes co-issue, m114).
// V A-frags for chunk nc+1 reloaded right after each af[ks]'s last use.
__global__ __launch_bounds__(512, 4) void attn_kernel(
    const unsigned short* __restrict__ q_t, const unsigned short* __restrict__ k_th,
    const unsigned short* __restrict__ k_tl, const unsigned short* __restrict__ v,
    const float* __restrict__ x, const float* __restrict__ gamma,
    float* __restrict__ out)
{
  __shared__ __align__(16) unsigned short ps[2][TM][PSTRIDE];
  __shared__ float rsp[4][TM];
  __shared__ float rsn[TM];

  const int b = blockIdx.x;           // batch -> XCD affinity
  const int m0 = blockIdx.y * TM;
  const int tid = threadIdx.x;
  const int w = tid >> 6;
  const int l = tid & 63;
  const int l31 = l & 31, lh = l >> 5;
  const int mt = w >> 2, nt = w & 3;  // QK score tile of this wave
  const int ncol = nt * 32 + l31;

  const short8 aq = *reinterpret_cast<const short8*>(
      q_t + ((size_t)b * N_ + m0 + 32 * mt + l31) * 16 + lh * 8);

  const unsigned short* vrow = v + ((size_t)b * C_ + w * 32 + l31) * N_;
  const unsigned short* kbh = k_th + (size_t)b * N_ * 8;
  const unsigned short* kbl = k_tl + (size_t)b * N_ * 8;

  float16 o0, o1;
  float rsum[16];
  #pragma unroll
  for (int r = 0; r < 16; ++r) { o0[r] = 0.f; o1[r] = 0.f; rsum[r] = 0.f; }

  // prologue: prefetch af(chunk0); QK+exp chunk0 -> ps[0]
  short8 af[8];
  #pragma unroll
  for (int g = 0; g < 8; ++g)
    af[g] = *reinterpret_cast<const short8*>(vrow + g * 16 + lh * 8);
  {
    const short8 bh = *reinterpret_cast<const short8*>(kbh + (size_t)ncol * 8);
    const short8 bl = *reinterpret_cast<const short8*>(kbl + (size_t)ncol * 8);
    float16 s;
    #pragma unroll
    for (int r = 0; r < 16; ++r) s[r] = 0.f;
    s = __builtin_amdgcn_mfma_f32_32x32x16_bf16(aq, bh, s, 0, 0, 0);
    s = __builtin_amdgcn_mfma_f32_32x32x16_bf16(aq, bl, s, 0, 0, 0);
    #pragma unroll
    for (int r = 0; r < 16; ++r) {
      const float e = exp2f(s[r]);
      rsum[r] += e;
      const int mrow = 32 * mt + (r & 3) + 8 * (r >> 2) + 4 * lh;
      ps[0][mrow][ncol] = f2bf(e);
    }
  }
  __syncthreads();

  for (int nc = 0; nc < NCH; ++nc) {
    const int buf = nc & 1;
    const bool more = (nc + 1) < NCH;
    const int n1 = more ? (nc + 1) * TN : 0;   // dummy 0 when done (in-bounds)

    // next chunk's k-frags (consumed below; latency hidden under PV)
    const short8 bh = *reinterpret_cast<const short8*>(kbh + (size_t)(n1 + ncol) * 8);
    const short8 bl = *reinterpret_cast<const short8*>(kbl + (size_t)(n1 + ncol) * 8);

    // --- PV chunk nc + af reload for chunk nc+1 ---
    #pragma unroll
    for (int ks = 0; ks < 8; ++ks) {
      const short8 p0 = *reinterpret_cast<const short8*>(&ps[buf][l31][ks * 16 + lh * 8]);
      const short8 p1 = *reinterpret_cast<const short8*>(&ps[buf][32 + l31][ks * 16 + lh * 8]);
      o0 = __builtin_amdgcn_mfma_f32_32x32x16_bf16(af[ks], p0, o0, 0, 0, 0);
      o1 = __builtin_amdgcn_mfma_f32_32x32x16_bf16(af[ks], p1, o1, 0, 0, 0);
      af[ks] = *reinterpret_cast<const short8*>(vrow + n1 + ks * 16 + lh * 8);
    }

    // --- QK + exp of chunk nc+1 into ps[buf^1] ---
    if (more) {
      float16 s;
      #pragma unroll
      for (int r = 0; r < 16; ++r) s[r] = 0.f;
      s = __builtin_amdgcn_mfma_f32_32x32x16_bf16(aq, bh, s, 0, 0, 0);
      s = __builtin_amdgcn_mfma_f32_32x32x16_bf16(aq, bl, s, 0, 0, 0);
      #pragma unroll
      for (int r = 0; r < 16; ++r) {
        const float e = exp2f(s[r]);
        rsum[r] += e;
        const int mrow = 32 * mt + (r & 3) + 8 * (r >> 2) + 4 * lh;
        ps[buf ^ 1][mrow][ncol] = f2bf(e);
      }
    }
    __syncthreads();
  }

  // --- row sums: reduce over the 32 n-lanes, stash per nt-wave, combine ---
  #pragma unroll
  for (int r = 0; r < 16; ++r) {
    float ss = rsum[r];
    #pragma unroll
    for (int off = 16; off >= 1; off >>= 1) ss += __shfl_xor(ss, off);
    rsum[r] = ss;
  }
  if (l31 == 0) {
    #pragma unroll
    for (int r = 0; r < 16; ++r) {
      const int mrow = 32 * mt + (r & 3) + 8 * (r >> 2) + 4 * lh;
      rsp[nt][mrow] = rsum[r];
    }
  }
  __syncthreads();
  if (tid < TM) rsn[tid] = rsp[0][tid] + rsp[1][tid] + rsp[2][tid] + rsp[3][tid];
  __syncthreads();

  // --- epilogue: out = gamma/rowsum * O + x ---
  const float g = gamma[0];
  const float t0 = g / rsn[l31];
  const float t1 = g / rsn[32 + l31];
  #pragma unroll
  for (int r = 0; r < 16; ++r) {
    const int c = 32 * w + (r & 3) + 8 * (r >> 2) + 4 * lh;
    const size_t i0 = ((size_t)b * C_ + c) * N_ + m0 + l31;
    out[i0]      = fmaf(o0[r], t0, x[i0]);
    out[i0 + 32] = fmaf(o1[r], t1, x[i0 + 32]);
  }
}

}  // namespace

extern "C" void kernel_launch(void* const* d_in, const int* in_sizes, int n_in,
                              void* d_out, int out_size, void* d_ws, size_t ws_size,
                              hipStream_t stream) {
  const float* x     = (const float*)d_in[0];
  const float* wq    = (const float*)d_in[1];
  const float* bq    = (const float*)d_in[2];
  const float* wk    = (const float*)d_in[3];
  const float* bk    = (const float*)d_in[4];
  const float* wv    = (const float*)d_in[5];
  const float* bv    = (const float*)d_in[6];
  const float* gamma = (const float*)d_in[7];
  float* out = (float*)d_out;

  // ws: q_t 1MB | k_th .5MB | k_tl .5MB | wv_bf 128KB | wqk_bf 16KB | v 16MB
  char* p = (char*)d_ws;
  unsigned short* q_t    = (unsigned short*)p;  p += (size_t)B_ * N_ * 16 * 2;
  unsigned short* k_th   = (unsigned short*)p;  p += (size_t)B_ * N_ * 8 * 2;
  unsigned short* k_tl   = (unsigned short*)p;  p += (size_t)B_ * N_ * 8 * 2;
  unsigned short* wv_bf  = (unsigned short*)p;  p += (size_t)C_ * C_ * 2;
  unsigned short* wqk_bf = (unsigned short*)p;  p += (size_t)32 * C_ * 2;
  unsigned short* v      = (unsigned short*)p;

  prep_kernel<<<dim3(C_ * C_ / 256), 256, 0, stream>>>(wv, wq, wk, wv_bf, wqk_bf);
  proj_kernel<<<dim3(N_ / 32, B_), 256, 0, stream>>>(x, bq, bk, wqk_bf, wv_bf, bv,
                                                     q_t, k_th, k_tl, v);
  attn_kernel<<<dim3(B_, N_ / TM), 512, 0, stream>>>(q_t, k_th, k_tl, v, x, gamma, out);
}

// Round 8
// 211.507 us; speedup vs baseline: 1.1527x; 1.1527x over previous
//
#include <hip/hip_runtime.h>
#include <math.h>

namespace {

constexpr int B_ = 8;
constexpr int C_ = 256;
constexpr int N_ = 4096;

constexpr int TM = 64;    // m-rows per attn block
constexpr int TN = 128;   // n-chunk per iteration
constexpr int NCH = N_ / TN;
constexpr int PSTRIDE = 136;  // ps row stride in bf16 (16B-aligned rows)
constexpr float LOG2E = 1.4426950408889634f;

// V tiled layout: v_t[b][nblk][c][nin], nblk=n/16, nin=n%16.
// An attn A-frag (lane c=l31, half lh) reads 16B at ((nblk*C + c)*16 + lh*8):
// consecutive lanes are 32B apart, lh fills the gaps -> one contiguous 1KB
// segment per instruction (vs 64 scattered lines with row-major V).
constexpr int VBLK = C_ * 16;   // elements per nblk

typedef __attribute__((ext_vector_type(8))) short short8;    // 8 bf16
typedef __attribute__((ext_vector_type(16))) float float16;  // 16 fp32 acc

__device__ inline unsigned short f2bf(float f) {
  unsigned u = __float_as_uint(f);
  u += 0x7FFFu + ((u >> 16) & 1u);   // RNE
  return (unsigned short)(u >> 16);
}
__device__ inline float bf2f(unsigned short h) {
  return __uint_as_float(((unsigned)h) << 16);
}

// ---- prep: wv -> bf16 ; wqk A-matrix [wq*log2e hi(8); lo(8); wk hi(8); lo(8)] ----
__global__ __launch_bounds__(256) void prep_kernel(
    const float* __restrict__ wv, const float* __restrict__ wq,
    const float* __restrict__ wk,
    unsigned short* __restrict__ wv_bf, unsigned short* __restrict__ wqk_bf) {
  const int i = blockIdx.x * 256 + threadIdx.x;   // grid 256 -> 65536 threads
  wv_bf[i] = f2bf(wv[i]);
  if (i < 2048) {
    const int d = i >> 8, c = i & 255;
    const float qL = wq[i] * LOG2E;
    const unsigned short hq = f2bf(qL);
    wqk_bf[d * 256 + c]        = hq;
    wqk_bf[(d + 8) * 256 + c]  = f2bf(qL - bf2f(hq));
    const float kv = wk[i];
    const unsigned short hk = f2bf(kv);
    wqk_bf[(d + 16) * 256 + c] = hk;
    wqk_bf[(d + 24) * 256 + c] = f2bf(kv - bf2f(hk));
  }
}

// Build a bf16 B-fragment (8 consecutive k=c values at column n) from fp32 LDS.
__device__ inline short8 xfrag(const float* xs, int c0, int n) {
  short8 r;
  #pragma unroll
  for (int i = 0; i < 8; ++i) r[i] = (short)f2bf(xs[(c0 + i) * 32 + n]);
  return r;
}

// ---- fused projection, all-MFMA, async-staged; V written in tiled layout ----
__global__ __launch_bounds__(256, 4) void proj_kernel(
    const float* __restrict__ x,
    const float* __restrict__ bq, const float* __restrict__ bk,
    const unsigned short* __restrict__ wqk_bf,
    const unsigned short* __restrict__ wv_bf, const float* __restrict__ bv,
    unsigned short* __restrict__ q_t, unsigned short* __restrict__ k_th,
    unsigned short* __restrict__ k_tl, unsigned short* __restrict__ v)
{
  __shared__ float xs[256 * 32];   // [c][n] fp32, 32 KB

  const int b = blockIdx.y;
  const int n0 = blockIdx.x * 32;
  const int tid = threadIdx.x;
  const int w = tid >> 6, l = tid & 63;
  const int l31 = l & 31, lh = l >> 5;

  // async stage: wave w covers c rows [64w, 64w+64), 2 rows per instruction
  {
    const int c_off = l >> 5, nn = l & 31;
    const float* gp = x + ((size_t)b * C_ + w * 64 + c_off) * N_ + n0 + nn;
    const float* lp = xs + (w * 64) * 32;
    #pragma unroll
    for (int i = 0; i < 64; i += 2) {
      __builtin_amdgcn_global_load_lds(
          (const __attribute__((address_space(1))) void*)(gp + (size_t)i * N_),
          (__attribute__((address_space(3))) void*)(lp + i * 32), 4, 0, 0);
    }
  }
  __syncthreads();   // drains vmcnt before barrier

  // q/k MFMA: wave 0 only -> D[32 d-rows][32 n]
  if (w == 0) {
    float16 sacc;
    #pragma unroll
    for (int r = 0; r < 16; ++r) sacc[r] = 0.f;
    for (int ks = 0; ks < 16; ++ks) {
      const short8 a = *reinterpret_cast<const short8*>(
          wqk_bf + l31 * 256 + ks * 16 + lh * 8);
      const short8 bfg = xfrag(xs, ks * 16 + lh * 8, l31);
      sacc = __builtin_amdgcn_mfma_f32_32x32x16_bf16(a, bfg, sacc, 0, 0, 0);
    }
    // rows: d=q_hi, d+8=q_lo, d+16=k_hi, d+24=k_lo ; lane holds d = r+4*lh, r<4
    const size_t gn = (size_t)b * N_ + n0 + l31;
    #pragma unroll
    for (int r = 0; r < 4; ++r) {
      const int d = r + 4 * lh;
      const float qv = sacc[r] + sacc[r + 4] + bq[d] * LOG2E;
      const unsigned short hq = f2bf(qv);
      q_t[gn * 16 + d]     = hq;
      q_t[gn * 16 + 8 + d] = f2bf(qv - bf2f(hq));
      const float kv = sacc[r + 8] + sacc[r + 12] + bk[d];
      const unsigned short hk = f2bf(kv);
      k_th[gn * 8 + d] = hk;
      k_tl[gn * 8 + d] = f2bf(kv - bf2f(hk));
    }
  }

  // V: wave w -> c_out [64w, 64w+64) x n [0,32): 2 accs of 32x32
  float16 acc[2];
  #pragma unroll
  for (int mi = 0; mi < 2; ++mi)
    #pragma unroll
    for (int r = 0; r < 16; ++r) acc[mi][r] = 0.f;

  for (int ks = 0; ks < 16; ++ks) {
    short8 af[2];
    #pragma unroll
    for (int mi = 0; mi < 2; ++mi)
      af[mi] = *reinterpret_cast<const short8*>(
          wv_bf + (w * 64 + mi * 32 + l31) * C_ + ks * 16 + lh * 8);
    const short8 bfg = xfrag(xs, ks * 16 + lh * 8, l31);
    #pragma unroll
    for (int mi = 0; mi < 2; ++mi)
      acc[mi] = __builtin_amdgcn_mfma_f32_32x32x16_bf16(af[mi], bfg, acc[mi], 0, 0, 0);
  }

  // write V in tiled layout: v_t[b][nblk][c][nin]
  #pragma unroll
  for (int mi = 0; mi < 2; ++mi)
    #pragma unroll
    for (int r = 0; r < 16; ++r) {
      const int c = w * 64 + mi * 32 + (r & 3) + 8 * (r >> 2) + 4 * lh;
      const int n = n0 + l31;
      const int nblk = n >> 4, nin = n & 15;
      v[(((size_t)b * (N_ / 16) + nblk) * C_ + c) * 16 + nin] =
          f2bf(acc[mi][r] + bv[c]);
    }
}

// ---- fused attention, barrier-pipelined, tiled-V coalesced A-frags ----
__global__ __launch_bounds__(512, 4) void attn_kernel(
    const unsigned short* __restrict__ q_t, const unsigned short* __restrict__ k_th,
    const unsigned short* __restrict__ k_tl, const unsigned short* __restrict__ v,
    const float* __restrict__ x, const float* __restrict__ gamma,
    float* __restrict__ out)
{
  __shared__ __align__(16) unsigned short ps[2][TM][PSTRIDE];
  __shared__ float rsp[4][TM];
  __shared__ float rsn[TM];

  const int b = blockIdx.x;           // batch -> XCD affinity
  const int m0 = blockIdx.y * TM;
  const int tid = threadIdx.x;
  const int w = tid >> 6;
  const int l = tid & 63;
  const int l31 = l & 31, lh = l >> 5;
  const int mt = w >> 2, nt = w & 3;  // QK score tile of this wave
  const int ncol = nt * 32 + l31;

  const short8 aq = *reinterpret_cast<const short8*>(
      q_t + ((size_t)b * N_ + m0 + 32 * mt + l31) * 16 + lh * 8);

  // per-lane base into tiled V: batch b, c = 32w+l31, half lh
  const unsigned short* vlane =
      v + ((size_t)b * (N_ / 16)) * VBLK + (size_t)(w * 32 + l31) * 16 + lh * 8;
  const unsigned short* kbh = k_th + (size_t)b * N_ * 8;
  const unsigned short* kbl = k_tl + (size_t)b * N_ * 8;

  float16 o0, o1;
  float rsum[16];
  #pragma unroll
  for (int r = 0; r < 16; ++r) { o0[r] = 0.f; o1[r] = 0.f; rsum[r] = 0.f; }

  // prologue: prefetch af(chunk0); QK+exp chunk0 -> ps[0]
  short8 af[8];
  #pragma unroll
  for (int g = 0; g < 8; ++g)
    af[g] = *reinterpret_cast<const short8*>(vlane + (size_t)g * VBLK);
  {
    const short8 bh = *reinterpret_cast<const short8*>(kbh + (size_t)ncol * 8);
    const short8 bl = *reinterpret_cast<const short8*>(kbl + (size_t)ncol * 8);
    float16 s;
    #pragma unroll
    for (int r = 0; r < 16; ++r) s[r] = 0.f;
    s = __builtin_amdgcn_mfma_f32_32x32x16_bf16(aq, bh, s, 0, 0, 0);
    s = __builtin_amdgcn_mfma_f32_32x32x16_bf16(aq, bl, s, 0, 0, 0);
    #pragma unroll
    for (int r = 0; r < 16; ++r) {
      const float e = exp2f(s[r]);
      rsum[r] += e;
      const int mrow = 32 * mt + (r & 3) + 8 * (r >> 2) + 4 * lh;
      ps[0][mrow][ncol] = f2bf(e);
    }
  }
  __syncthreads();

  for (int nc = 0; nc < NCH; ++nc) {
    const int buf = nc & 1;
    const bool more = (nc + 1) < NCH;
    const int nc1 = more ? (nc + 1) : 0;      // dummy chunk 0 when done
    const int n1 = nc1 * TN;

    // next chunk's k-frags (consumed below; latency hidden under PV)
    const short8 bh = *reinterpret_cast<const short8*>(kbh + (size_t)(n1 + ncol) * 8);
    const short8 bl = *reinterpret_cast<const short8*>(kbl + (size_t)(n1 + ncol) * 8);

    // --- PV chunk nc + af reload for chunk nc+1 (coalesced tiled-V) ---
    #pragma unroll
    for (int ks = 0; ks < 8; ++ks) {
      const short8 p0 = *reinterpret_cast<const short8*>(&ps[buf][l31][ks * 16 + lh * 8]);
      const short8 p1 = *reinterpret_cast<const short8*>(&ps[buf][32 + l31][ks * 16 + lh * 8]);
      o0 = __builtin_amdgcn_mfma_f32_32x32x16_bf16(af[ks], p0, o0, 0, 0, 0);
      o1 = __builtin_amdgcn_mfma_f32_32x32x16_bf16(af[ks], p1, o1, 0, 0, 0);
      af[ks] = *reinterpret_cast<const short8*>(vlane + (size_t)(nc1 * 8 + ks) * VBLK);
    }

    // --- QK + exp of chunk nc+1 into ps[buf^1] ---
    if (more) {
      float16 s;
      #pragma unroll
      for (int r = 0; r < 16; ++r) s[r] = 0.f;
      s = __builtin_amdgcn_mfma_f32_32x32x16_bf16(aq, bh, s, 0, 0, 0);
      s = __builtin_amdgcn_mfma_f32_32x32x16_bf16(aq, bl, s, 0, 0, 0);
      #pragma unroll
      for (int r = 0; r < 16; ++r) {
        const float e = exp2f(s[r]);
        rsum[r] += e;
        const int mrow = 32 * mt + (r & 3) + 8 * (r >> 2) + 4 * lh;
        ps[buf ^ 1][mrow][ncol] = f2bf(e);
      }
    }
    __syncthreads();
  }

  // --- row sums: reduce over the 32 n-lanes, stash per nt-wave, combine ---
  #pragma unroll
  for (int r = 0; r < 16; ++r) {
    float ss = rsum[r];
    #pragma unroll
    for (int off = 16; off >= 1; off >>= 1) ss += __shfl_xor(ss, off);
    rsum[r] = ss;
  }
  if (l31 == 0) {
    #pragma unroll
    for (int r = 0; r < 16; ++r) {
      const int mrow = 32 * mt + (r & 3) + 8 * (r >> 2) + 4 * lh;
      rsp[nt][mrow] = rsum[r];
    }
  }
  __syncthreads();
  if (tid < TM) rsn[tid] = rsp[0][tid] + rsp[1][tid] + rsp[2][tid] + rsp[3][tid];
  __syncthreads();

  // --- epilogue: out = gamma/rowsum * O + x ---
  const float g = gamma[0];
  const float t0 = g / rsn[l31];
  const float t1 = g / rsn[32 + l31];
  #pragma unroll
  for (int r = 0; r < 16; ++r) {
    const int c = 32 * w + (r & 3) + 8 * (r >> 2) + 4 * lh;
    const size_t i0 = ((size_t)b * C_ + c) * N_ + m0 + l31;
    out[i0]      = fmaf(o0[r], t0, x[i0]);
    out[i0 + 32] = fmaf(o1[r], t1, x[i0 + 32]);
  }
}

}  // namespace

extern "C" void kernel_launch(void* const* d_in, const int* in_sizes, int n_in,
                              void* d_out, int out_size, void* d_ws, size_t ws_size,
                              hipStream_t stream) {
  const float* x     = (const float*)d_in[0];
  const float* wq    = (const float*)d_in[1];
  const float* bq    = (const float*)d_in[2];
  const float* wk    = (const float*)d_in[3];
  const float* bk    = (const float*)d_in[4];
  const float* wv    = (const float*)d_in[5];
  const float* bv    = (const float*)d_in[6];
  const float* gamma = (const float*)d_in[7];
  float* out = (float*)d_out;

  // ws: q_t 1MB | k_th .5MB | k_tl .5MB | wv_bf 128KB | wqk_bf 16KB | v 16MB
  char* p = (char*)d_ws;
  unsigned short* q_t    = (unsigned short*)p;  p += (size_t)B_ * N_ * 16 * 2;
  unsigned short* k_th   = (unsigned short*)p;  p += (size_t)B_ * N_ * 8 * 2;
  unsigned short* k_tl   = (unsigned short*)p;  p += (size_t)B_ * N_ * 8 * 2;
  unsigned short* wv_bf  = (unsigned short*)p;  p += (size_t)C_ * C_ * 2;
  unsigned short* wqk_bf = (unsigned short*)p;  p += (size_t)32 * C_ * 2;
  unsigned short* v      = (unsigned short*)p;

  prep_kernel<<<dim3(C_ * C_ / 256), 256, 0, stream>>>(wv, wq, wk, wv_bf, wqk_bf);
  proj_kernel<<<dim3(N_ / 32, B_), 256, 0, stream>>>(x, bq, bk, wqk_bf, wv_bf, bv,
                                                     q_t, k_th, k_tl, v);
  attn_kernel<<<dim3(B_, N_ / TM), 512, 0, stream>>>(q_t, k_th, k_tl, v, x, gamma, out);
}